// Round 2
// baseline (672.917 us; speedup 1.0000x reference)
//
#include <hip/hip_runtime.h>
#include <math.h>

// Problem constants
#define BB 32
#define NN 256
#define FF 12
// ws layout (in floats)
#define WS_SUMS   0                    // 1024: sum_d, sumsq_d, sum_r, sumsq_r (256 each)
#define WS_STATS  1024                 // 1024: mean_d, istd_d, mean_r, istd_r (256 each)
#define WS_W2P    2048                 // 1024: W2 repacked [32][32] (m padded 30->32 with 0)
#define WS_B2P    3072                 // 32:  b2 padded
#define WS_USG    4096                 // 262144: us[b][i][32]
#define WS_UTPG   (WS_USG + 262144)    // 262144: ut'[b][j][32] = ut + c_a + b1
#define WS_AGG    (WS_UTPG + 262144)   // 262144: agg[b][n][32] (m 0..29 valid)

// fast sigmoid: v_exp_f32 + v_rcp_f32 (1-ulp). IEEE div would cost ~8 VALU ops.
__device__ __forceinline__ float sig(float x) {
    return __builtin_amdgcn_rcpf(1.0f + __expf(-x));
}

// ---- per-column (j) stats partial sums over (b,i) ----
__global__ __launch_bounds__(256) void colstats_kernel(
    const float* __restrict__ dist, const float* __restrict__ direc, float* __restrict__ sums)
{
    const int t = threadIdx.x;
    const int r0 = blockIdx.x * 32;          // 256 blocks x 32 rows of (b*N+i)
    float sd = 0.f, sdd = 0.f, sr = 0.f, srr = 0.f;
    for (int rr = 0; rr < 32; ++rr) {
        const float d  = dist [(r0 + rr) * NN + t];
        const float dr = direc[(r0 + rr) * NN + t];
        sd += d;  sdd = fmaf(d, d, sdd);
        sr += dr; srr = fmaf(dr, dr, srr);
    }
    atomicAdd(&sums[t],        sd);
    atomicAdd(&sums[256 + t],  sdd);
    atomicAdd(&sums[512 + t],  sr);
    atomicAdd(&sums[768 + t],  srr);
}

// ---- finalize stats (ddof=1) + repack W2/b2 ----
__global__ __launch_bounds__(256) void finalize_kernel(
    const float* __restrict__ sums, const float* __restrict__ W2, const float* __restrict__ b2,
    float* __restrict__ stats, float* __restrict__ W2p, float* __restrict__ b2p)
{
    const int t = threadIdx.x;
    const float M = (float)(BB * NN);
    {   // dist stats
        const float s = sums[t], q = sums[256 + t];
        const float mean = s / M;
        float var = (q - s * mean) / (M - 1.0f);
        if (var < 1e-20f) var = 1e-20f;
        stats[t] = mean; stats[256 + t] = rsqrtf(var);
    }
    {   // direc stats
        const float s = sums[512 + t], q = sums[768 + t];
        const float mean = s / M;
        float var = (q - s * mean) / (M - 1.0f);
        if (var < 1e-20f) var = 1e-20f;
        stats[512 + t] = mean; stats[768 + t] = rsqrtf(var);
    }
    for (int idx = t; idx < 1024; idx += 256) {
        const int k = idx >> 5, m = idx & 31;
        W2p[idx] = (m < 30) ? W2[k * 30 + m] : 0.0f;
    }
    if (t < 32) b2p[t] = (t < 30) ? b2[t] : 0.0f;
}

// ---- per-node projections: us = x@W1[0:12], ut' = x@W1[13:25] + c_a + b1 ----
__global__ __launch_bounds__(256) void node_pre_kernel(
    const float* __restrict__ x, const float* __restrict__ W1, const float* __restrict__ b1,
    float* __restrict__ usg, float* __restrict__ utpg)
{
    const int idx = blockIdx.x * 256 + threadIdx.x;   // 262144 threads
    const int r = idx >> 5, k = idx & 31;
    const float* xr = x + r * FF;
    float us = 0.f, ut = 0.f;
#pragma unroll
    for (int f = 0; f < FF; ++f) {
        const float xv = xr[f];
        us = fmaf(xv, W1[f * 32 + k], us);
        ut = fmaf(xv, W1[(13 + f) * 32 + k], ut);
    }
    const float ca = W1[12 * 32 + k] + W1[25 * 32 + k] + W1[27 * 32 + k]
                   + W1[29 * 32 + k] + W1[30 * 32 + k] + W1[31 * 32 + k];
    usg[idx]  = us;
    utpg[idx] = ut + ca + b1[k];
}

// ---- main edge kernel: block = (b, 8-row i-tile), threads = j ----
__global__ __launch_bounds__(256) void edge_kernel(
    const float* __restrict__ adj_dist, const float* __restrict__ adj_direct,
    const float* __restrict__ W1, const float* __restrict__ b1,
    const float* __restrict__ usg, const float* __restrict__ utpg,
    const float* __restrict__ stats, const float* __restrict__ W2p,
    const float* __restrict__ b2p, float* __restrict__ agg)
{
    __shared__ float us_s[8][32];
    __shared__ float r26s[32], r28s[32], b1s[32];
    __shared__ float W2s[32][32];      // layer-2 weights, wave-uniform ds_read broadcast
    __shared__ float b2s[32];
    __shared__ float mins[8][4][32];   // per-i, per-wave minus partials

    const int t    = threadIdx.x;
    const int b    = blockIdx.x >> 5;
    const int i0   = (blockIdx.x & 31) << 3;
    const int w    = t >> 6;
    const int lane = t & 63;

    { const int i = t >> 5, k = t & 31;
      us_s[i][k] = usg[((b << 8) + i0 + i) * 32 + k]; }
    if (t < 32) { r26s[t] = W1[26 * 32 + t]; r28s[t] = W1[28 * 32 + t]; b1s[t] = b1[t]; }
    for (int idx = t; idx < 1024; idx += 256) W2s[idx >> 5][idx & 31] = W2p[idx];
    if (t < 32) b2s[t] = b2p[t];
    __syncthreads();

    float4 utp[8];
    { const float4* uv = (const float4*)(utpg + ((b << 8) + t) * 32);
#pragma unroll
      for (int k4 = 0; k4 < 8; ++k4) utp[k4] = uv[k4]; }

    const float md  = stats[t];
    const float isd = stats[256 + t];
    const float mr  = stats[512 + t];
    const float isr = stats[768 + t];

    float accp[32];
#pragma unroll
    for (int m = 0; m < 32; ++m) accp[m] = 0.0f;

    const float* dptr = adj_dist   + (((b << 8) + i0) << 8) + t;
    const float* rptr = adj_direct + (((b << 8) + i0) << 8) + t;

#pragma unroll 1
    for (int i = 0; i < 8; ++i) {
        const float d  = dptr[i << 8];
        const float dr = rptr[i << 8];
        const bool  a  = (d != 0.0f);
        const float dn = (d - md) * isd;
        const float rn = (dr - mr) * isr;

        // layer 1 (rank-decomposed) + sigmoid
        float h[32];
#pragma unroll
        for (int k4 = 0; k4 < 8; ++k4) {
            const float4 us4 = *(const float4*)&us_s[i][k4 * 4];
            const float4 r26 = *(const float4*)&r26s[k4 * 4];
            const float4 r28 = *(const float4*)&r28s[k4 * 4];
            const float4 b14 = *(const float4*)&b1s[k4 * 4];
            const float4 u4  = utp[k4];
            float z0 = a ? (us4.x + u4.x) : b14.x;
            float z1 = a ? (us4.y + u4.y) : b14.y;
            float z2 = a ? (us4.z + u4.z) : b14.z;
            float z3 = a ? (us4.w + u4.w) : b14.w;
            z0 = fmaf(dn, r26.x, z0); z0 = fmaf(rn, r28.x, z0);
            z1 = fmaf(dn, r26.y, z1); z1 = fmaf(rn, r28.y, z1);
            z2 = fmaf(dn, r26.z, z2); z2 = fmaf(rn, r28.z, z2);
            z3 = fmaf(dn, r26.w, z3); z3 = fmaf(rn, r28.w, z3);
            h[k4 * 4 + 0] = sig(z0);
            h[k4 * 4 + 1] = sig(z1);
            h[k4 * 4 + 2] = sig(z2);
            h[k4 * 4 + 3] = sig(z3);
        }

        // layer 2: e = sigmoid(h @ W2 + b2), m padded to 32 (cols 30,31 are zero)
        float e[32];
#pragma unroll
        for (int m = 0; m < 32; ++m) e[m] = b2s[m];
#pragma unroll
        for (int k = 0; k < 32; ++k) {
            const float hk = h[k];
#pragma unroll
            for (int m = 0; m < 32; ++m) e[m] = fmaf(hk, W2s[k][m], e[m]);
        }
#pragma unroll
        for (int m = 0; m < 30; ++m) e[m] = sig(e[m]);
        e[30] = 0.0f; e[31] = 0.0f;    // mask padded outputs (sig(0)=0.5 otherwise)

        // plus part (thread-local over i; j = t fixed)
#pragma unroll
        for (int m = 0; m < 32; ++m) accp[m] += e[m];

        // minus part: multi-value wave reduce. Stage s: each lane keeps half its
        // values, exchanges the discarded half. 16+8+4+2+1+1 = 32 shuffles total
        // (vs 192 for a per-value butterfly). Lane l ends with the 64-lane total
        // for m = bitrev5(l & 31).
#define RSTAGE(S, CNT)                                                   \
        {   const bool hi = (lane >> (S)) & 1;                           \
            _Pragma("unroll")                                            \
            for (int r = 0; r < (CNT); ++r) {                            \
                const float send = hi ? e[r] : e[r + (CNT)];             \
                const float recv = __shfl_xor(send, 1 << (S));           \
                e[r] = (hi ? e[r + (CNT)] : e[r]) + recv;                \
            } }
        RSTAGE(0, 16) RSTAGE(1, 8) RSTAGE(2, 4) RSTAGE(3, 2) RSTAGE(4, 1)
#undef RSTAGE
        const float tot = e[0] + __shfl_xor(e[0], 32);
        if (lane < 32) mins[i][w][__brev((unsigned)lane) >> 27] = tot;
    }
    __syncthreads();

    // flush minus partials: thread -> (i, m)
    { const int i = t >> 5, m = t & 31;
      if (m < 30) {
          const float s = mins[i][0][m] + mins[i][1][m] + mins[i][2][m] + mins[i][3][m];
          atomicAdd(&agg[((b << 8) + i0 + i) * 32 + m], -s);
      } }

    // flush plus partials: thread owns n = t
    { float* ap = agg + ((b << 8) + t) * 32;
#pragma unroll
      for (int m = 0; m < 30; ++m) atomicAdd(&ap[m], accp[m]);
    }
}

// ---- node MLP: out = sigmoid(agg @ W3 + b3) ----
__global__ __launch_bounds__(256) void node_out_kernel(
    const float* __restrict__ agg, const float* __restrict__ W3, const float* __restrict__ b3,
    float* __restrict__ out)
{
    const int nloc = threadIdx.x >> 5;
    const int o    = threadIdx.x & 31;
    const int n    = blockIdx.x * 8 + nloc;    // n in [0, B*N)
    if (o < 12) {
        const float* ar = agg + n * 32;
        float acc = b3[o];
#pragma unroll
        for (int m = 0; m < 30; ++m) acc = fmaf(ar[m], W3[m * 12 + o], acc);
        out[n * 12 + o] = sig(acc);
    }
}

extern "C" void kernel_launch(void* const* d_in, const int* in_sizes, int n_in,
                              void* d_out, int out_size, void* d_ws, size_t ws_size,
                              hipStream_t stream)
{
    const float* x    = (const float*)d_in[0];
    const float* adjd = (const float*)d_in[1];
    const float* adjr = (const float*)d_in[2];
    // d_in[3], d_in[4]: wind_mean / wind_std — unused by the reference
    const float* W1   = (const float*)d_in[5];
    const float* b1   = (const float*)d_in[6];
    const float* W2   = (const float*)d_in[7];
    const float* b2   = (const float*)d_in[8];
    const float* W3   = (const float*)d_in[9];
    const float* b3   = (const float*)d_in[10];
    float* ws  = (float*)d_ws;
    float* out = (float*)d_out;

    hipMemsetAsync(ws + WS_SUMS, 0, 1024 * sizeof(float), stream);
    hipMemsetAsync(ws + WS_AGG,  0, 262144 * sizeof(float), stream);

    colstats_kernel<<<256, 256, 0, stream>>>(adjd, adjr, ws + WS_SUMS);
    finalize_kernel<<<1, 256, 0, stream>>>(ws + WS_SUMS, W2, b2,
                                           ws + WS_STATS, ws + WS_W2P, ws + WS_B2P);
    node_pre_kernel<<<1024, 256, 0, stream>>>(x, W1, b1, ws + WS_USG, ws + WS_UTPG);
    edge_kernel<<<1024, 256, 0, stream>>>(adjd, adjr, W1, b1,
                                          ws + WS_USG, ws + WS_UTPG,
                                          ws + WS_STATS, ws + WS_W2P, ws + WS_B2P,
                                          ws + WS_AGG);
    node_out_kernel<<<1024, 256, 0, stream>>>(ws + WS_AGG, W3, b3, out);
}

// Round 3
// 425.931 us; speedup vs baseline: 1.5799x; 1.5799x over previous
//
#include <hip/hip_runtime.h>
#include <math.h>

// Problem constants
#define BB 32
#define NN 256
#define FF 12
// ws layout (in floats)
#define WS_SUMS   0                    // 1024: sum_d, sumsq_d, sum_r, sumsq_r (256 each)
#define WS_STATS  1024                 // 1024: mean_d, istd_d, mean_r, istd_r (256 each)
#define WS_W2P    2048                 // 1024: W2 repacked [32][32] (m padded 30->32)
#define WS_B2P    3072                 // 32 (+pad to 1024)
#define WS_USG    4096                 // 262144: us[b][i][32]
#define WS_UTPG   (WS_USG + 262144)    // 262144: ut'[b][j][32] = ut + c_a + b1
#define WS_MIN    (WS_UTPG + 262144)   // 262144: minus[b][m][n]  (complete col-sums)
#define WS_PLUS   (WS_MIN + 262144)    // nit*262144: plus[b][it][m][j] partials

// fast sigmoid: v_exp_f32 + v_rcp_f32 (1-ulp each)
__device__ __forceinline__ float sig(float x) {
    return __builtin_amdgcn_rcpf(1.0f + __expf(-x));
}

// ---- per-column (j) stats partial sums over (b,i) ----
__global__ __launch_bounds__(256) void colstats_kernel(
    const float* __restrict__ dist, const float* __restrict__ direc, float* __restrict__ sums)
{
    const int t = threadIdx.x;
    const int r0 = blockIdx.x * 32;          // 256 blocks x 32 rows of (b*N+i)
    float sd = 0.f, sdd = 0.f, sr = 0.f, srr = 0.f;
    for (int rr = 0; rr < 32; ++rr) {
        const float d  = dist [(r0 + rr) * NN + t];
        const float dr = direc[(r0 + rr) * NN + t];
        sd += d;  sdd = fmaf(d, d, sdd);
        sr += dr; srr = fmaf(dr, dr, srr);
    }
    atomicAdd(&sums[t],        sd);
    atomicAdd(&sums[256 + t],  sdd);
    atomicAdd(&sums[512 + t],  sr);
    atomicAdd(&sums[768 + t],  srr);
}

// ---- finalize stats (ddof=1) + repack W2/b2 ----
__global__ __launch_bounds__(256) void finalize_kernel(
    const float* __restrict__ sums, const float* __restrict__ W2, const float* __restrict__ b2,
    float* __restrict__ stats, float* __restrict__ W2p, float* __restrict__ b2p)
{
    const int t = threadIdx.x;
    const float M = (float)(BB * NN);
    {   const float s = sums[t], q = sums[256 + t];
        const float mean = s / M;
        float var = (q - s * mean) / (M - 1.0f);
        if (var < 1e-20f) var = 1e-20f;
        stats[t] = mean; stats[256 + t] = rsqrtf(var);
    }
    {   const float s = sums[512 + t], q = sums[768 + t];
        const float mean = s / M;
        float var = (q - s * mean) / (M - 1.0f);
        if (var < 1e-20f) var = 1e-20f;
        stats[512 + t] = mean; stats[768 + t] = rsqrtf(var);
    }
    for (int idx = t; idx < 1024; idx += 256) {
        const int k = idx >> 5, m = idx & 31;
        W2p[idx] = (m < 30) ? W2[k * 30 + m] : 0.0f;
    }
    if (t < 32) b2p[t] = (t < 30) ? b2[t] : 0.0f;
}

// ---- per-node projections: us = x@W1[0:12], ut' = x@W1[13:25] + c_a + b1 ----
__global__ __launch_bounds__(256) void node_pre_kernel(
    const float* __restrict__ x, const float* __restrict__ W1, const float* __restrict__ b1,
    float* __restrict__ usg, float* __restrict__ utpg)
{
    const int idx = blockIdx.x * 256 + threadIdx.x;   // 262144 threads
    const int r = idx >> 5, k = idx & 31;
    const float* xr = x + r * FF;
    float us = 0.f, ut = 0.f;
#pragma unroll
    for (int f = 0; f < FF; ++f) {
        const float xv = xr[f];
        us = fmaf(xv, W1[f * 32 + k], us);
        ut = fmaf(xv, W1[(13 + f) * 32 + k], ut);
    }
    const float ca = W1[12 * 32 + k] + W1[25 * 32 + k] + W1[27 * 32 + k]
                   + W1[29 * 32 + k] + W1[30 * 32 + k] + W1[31 * 32 + k];
    usg[idx]  = us;
    utpg[idx] = ut + ca + b1[k];
}

// ---- main edge kernel: block = (b, R-row i-tile), threads = j ----
// NO global atomics: minus (col-sum over all j) is complete per block -> plain store;
// plus (row-sum over this block's i's) -> per-block partial, reduced later.
__global__ __launch_bounds__(256) void edge_part_kernel(
    const float* __restrict__ adj_dist, const float* __restrict__ adj_direct,
    const float* __restrict__ W1, const float* __restrict__ b1,
    const float* __restrict__ usg, const float* __restrict__ utpg,
    const float* __restrict__ stats, const float* __restrict__ W2p,
    const float* __restrict__ b2p, float* __restrict__ plus,
    float* __restrict__ minusv, int lognit)
{
    __shared__ float us_s[64][32];
    __shared__ float r26s[32], r28s[32], b1s[32], b2s[32];
    __shared__ float W2s[32][32];      // wave-uniform ds_read broadcast
    __shared__ float mins[64][4][32];  // per-i per-wave minus partials

    const int t    = threadIdx.x;
    const int nit  = 1 << lognit;          // i-tiles per batch
    const int R    = NN >> lognit;         // rows per block (16/32/64)
    const int b    = blockIdx.x >> lognit;
    const int it   = blockIdx.x & (nit - 1);
    const int i0   = it * R;
    const int w    = t >> 6;
    const int lane = t & 63;

    { const int k = t & 31;
      for (int ii = t >> 5; ii < R; ii += 8)
          us_s[ii][k] = usg[((b << 8) + i0 + ii) * 32 + k]; }
    if (t < 32) { r26s[t] = W1[26 * 32 + t]; r28s[t] = W1[28 * 32 + t];
                  b1s[t] = b1[t]; b2s[t] = b2p[t]; }
    for (int idx = t; idx < 1024; idx += 256) W2s[idx >> 5][idx & 31] = W2p[idx];
    __syncthreads();

    float4 utp[8];
    { const float4* uv = (const float4*)(utpg + ((b << 8) + t) * 32);
#pragma unroll
      for (int k4 = 0; k4 < 8; ++k4) utp[k4] = uv[k4]; }

    const float md  = stats[t];
    const float isd = stats[256 + t];
    const float mr  = stats[512 + t];
    const float isr = stats[768 + t];

    float accp[32];
#pragma unroll
    for (int m = 0; m < 32; ++m) accp[m] = 0.0f;

    const float* dptr = adj_dist   + (((b << 8) + i0) << 8) + t;
    const float* rptr = adj_direct + (((b << 8) + i0) << 8) + t;

#pragma unroll 1
    for (int i = 0; i < R; ++i) {
        const float d  = dptr[i << 8];
        const float dr = rptr[i << 8];
        const bool  a  = (d != 0.0f);
        const float dn = (d - md) * isd;
        const float rn = (dr - mr) * isr;

        // layer 1 (rank-decomposed) + sigmoid
        float h[32];
#pragma unroll
        for (int k4 = 0; k4 < 8; ++k4) {
            const float4 us4 = *(const float4*)&us_s[i][k4 * 4];
            const float4 r26 = *(const float4*)&r26s[k4 * 4];
            const float4 r28 = *(const float4*)&r28s[k4 * 4];
            const float4 b14 = *(const float4*)&b1s[k4 * 4];
            const float4 u4  = utp[k4];
            float z0 = a ? (us4.x + u4.x) : b14.x;
            float z1 = a ? (us4.y + u4.y) : b14.y;
            float z2 = a ? (us4.z + u4.z) : b14.z;
            float z3 = a ? (us4.w + u4.w) : b14.w;
            z0 = fmaf(dn, r26.x, z0); z0 = fmaf(rn, r28.x, z0);
            z1 = fmaf(dn, r26.y, z1); z1 = fmaf(rn, r28.y, z1);
            z2 = fmaf(dn, r26.z, z2); z2 = fmaf(rn, r28.z, z2);
            z3 = fmaf(dn, r26.w, z3); z3 = fmaf(rn, r28.w, z3);
            h[k4 * 4 + 0] = sig(z0);
            h[k4 * 4 + 1] = sig(z1);
            h[k4 * 4 + 2] = sig(z2);
            h[k4 * 4 + 3] = sig(z3);
        }

        // layer 2: e = sigmoid(h @ W2 + b2), m padded to 32 (cols 30,31 zero)
        float e[32];
#pragma unroll
        for (int m = 0; m < 32; ++m) e[m] = b2s[m];
#pragma unroll
        for (int k = 0; k < 32; ++k) {
            const float hk = h[k];
#pragma unroll
            for (int m = 0; m < 32; ++m) e[m] = fmaf(hk, W2s[k][m], e[m]);
        }
#pragma unroll
        for (int m = 0; m < 30; ++m) e[m] = sig(e[m]);
        e[30] = 0.0f; e[31] = 0.0f;

        // plus part (thread-local; j = t fixed)
#pragma unroll
        for (int m = 0; m < 32; ++m) accp[m] += e[m];

        // minus part: multi-value wave reduce (32 shuffles for 32 values).
        // Lane l ends with the 64-lane total for m = bitrev5(l & 31).
#define RSTAGE(S, CNT)                                                   \
        {   const bool hi = (lane >> (S)) & 1;                           \
            _Pragma("unroll")                                            \
            for (int r = 0; r < (CNT); ++r) {                            \
                const float send = hi ? e[r] : e[r + (CNT)];             \
                const float recv = __shfl_xor(send, 1 << (S));           \
                e[r] = (hi ? e[r + (CNT)] : e[r]) + recv;                \
            } }
        RSTAGE(0, 16) RSTAGE(1, 8) RSTAGE(2, 4) RSTAGE(3, 2) RSTAGE(4, 1)
#undef RSTAGE
        const float tot = e[0] + __shfl_xor(e[0], 32);
        if (lane < 32) mins[i][w][__brev((unsigned)lane) >> 27] = tot;
    }
    __syncthreads();

    // minus flush: complete col-sums for this block's rows -> plain stores
    { const int m = t & 31;
      if (m < 30)
          for (int ii = t >> 5; ii < R; ii += 8) {
              const float s = mins[ii][0][m] + mins[ii][1][m]
                            + mins[ii][2][m] + mins[ii][3][m];
              minusv[((b << 5) + m) * 256 + i0 + ii] = s;
          } }

    // plus flush: per-block partial, coalesced (lane-consecutive j)
    { const int base = ((b << lognit) + it) << 13;   // (b*nit+it)*32*256
#pragma unroll
      for (int m = 0; m < 30; ++m)
          plus[base + (m << 8) + t] = accp[m];
    }
}

// ---- reduce partials + node MLP, fused ----
__global__ __launch_bounds__(256) void reduce_out_kernel(
    const float* __restrict__ plus, const float* __restrict__ minusv,
    const float* __restrict__ W3, const float* __restrict__ b3,
    float* __restrict__ out, int lognit)
{
    const int b = blockIdx.x;
    const int n = threadIdx.x;
    const int nit = 1 << lognit;

    float acc[30];
#pragma unroll
    for (int m = 0; m < 30; ++m) acc[m] = -minusv[((b << 5) + m) * 256 + n];
#pragma unroll 1
    for (int it = 0; it < nit; ++it) {
        const float* p = plus + (((b << lognit) + it) << 13) + n;
#pragma unroll
        for (int m = 0; m < 30; ++m) acc[m] += p[m << 8];
    }
    float* op = out + ((b << 8) + n) * 12;
#pragma unroll
    for (int o = 0; o < 12; ++o) {
        float z = b3[o];
#pragma unroll
        for (int m = 0; m < 30; ++m) z = fmaf(acc[m], W3[m * 12 + o], z);
        op[o] = sig(z);
    }
}

extern "C" void kernel_launch(void* const* d_in, const int* in_sizes, int n_in,
                              void* d_out, int out_size, void* d_ws, size_t ws_size,
                              hipStream_t stream)
{
    const float* x    = (const float*)d_in[0];
    const float* adjd = (const float*)d_in[1];
    const float* adjr = (const float*)d_in[2];
    const float* W1   = (const float*)d_in[5];
    const float* b1   = (const float*)d_in[6];
    const float* W2   = (const float*)d_in[7];
    const float* b2   = (const float*)d_in[8];
    const float* W3   = (const float*)d_in[9];
    const float* b3   = (const float*)d_in[10];
    float* ws  = (float*)d_ws;
    float* out = (float*)d_out;

    // pick i-tile count from available scratch (deterministic across calls)
    int lognit = 2;                                            //  64 rows/blk, 7.4 MB
    if      (ws_size >= ((size_t)WS_PLUS + 16u * 262144u) * 4u) lognit = 4;  // 16 rows, 20 MB
    else if (ws_size >= ((size_t)WS_PLUS +  8u * 262144u) * 4u) lognit = 3;  // 32 rows, 11.6 MB

    hipMemsetAsync(ws + WS_SUMS, 0, 1024 * sizeof(float), stream);

    colstats_kernel<<<256, 256, 0, stream>>>(adjd, adjr, ws + WS_SUMS);
    finalize_kernel<<<1, 256, 0, stream>>>(ws + WS_SUMS, W2, b2,
                                           ws + WS_STATS, ws + WS_W2P, ws + WS_B2P);
    node_pre_kernel<<<1024, 256, 0, stream>>>(x, W1, b1, ws + WS_USG, ws + WS_UTPG);
    edge_part_kernel<<<BB << lognit, 256, 0, stream>>>(adjd, adjr, W1, b1,
                                                       ws + WS_USG, ws + WS_UTPG,
                                                       ws + WS_STATS, ws + WS_W2P,
                                                       ws + WS_B2P, ws + WS_PLUS,
                                                       ws + WS_MIN, lognit);
    reduce_out_kernel<<<BB, 256, 0, stream>>>(ws + WS_PLUS, ws + WS_MIN,
                                              W3, b3, out, lognit);
}

// Round 5
// 166.250 us; speedup vs baseline: 4.0476x; 2.5620x over previous
//
#include <hip/hip_runtime.h>
#include <hip/hip_bf16.h>
#include <math.h>

// Problem constants
#define BB 32
#define NN 256
#define FF 12
// ws layout (in floats)
#define WS_SUMS   0                    // 1024: sum_d, sumsq_d, sum_r, sumsq_r (256 each)
#define WS_STATS  1024                 // 1024: mean_d, istd_d, mean_r, istd_r (256 each)
#define WS_W2P    2048                 // 1024: W2 repacked [32][32] (m padded 30->32)
#define WS_B2P    3072                 // 32 (+pad to 1024)
#define WS_USG    4096                 // 262144: us[b][i][32]
#define WS_UTPG   (WS_USG + 262144)    // 262144: ut'[b][j][32] = ut + c_a + b1
#define WS_MIN    (WS_UTPG + 262144)   // 262144: minus[b][m][n]  (complete col-sums)
#define WS_PLUS   (WS_MIN + 262144)    // nit*262144: plus[b][it][m][j] partials

typedef __attribute__((ext_vector_type(8))) short bf16x8;
typedef __attribute__((ext_vector_type(4))) float f32x4;

// fast sigmoid: v_exp_f32 + v_rcp_f32
__device__ __forceinline__ float sig(float x) {
    return __builtin_amdgcn_rcpf(1.0f + __expf(-x));
}
__device__ __forceinline__ short f2bf(float x) {
    __hip_bfloat16 b = __float2bfloat16(x);   // RTN-even
    short s; __builtin_memcpy(&s, &b, 2); return s;
}
__device__ __forceinline__ float bf2f(short s) {
    __hip_bfloat16 b; __builtin_memcpy(&b, &s, 2);
    return __bfloat162float(b);
}

// ---- per-column (j) stats partial sums over (b,i) ----
__global__ __launch_bounds__(256) void colstats_kernel(
    const float* __restrict__ dist, const float* __restrict__ direc, float* __restrict__ sums)
{
    const int t = threadIdx.x;
    const int r0 = blockIdx.x * 32;
    float sd = 0.f, sdd = 0.f, sr = 0.f, srr = 0.f;
    for (int rr = 0; rr < 32; ++rr) {
        const float d  = dist [(r0 + rr) * NN + t];
        const float dr = direc[(r0 + rr) * NN + t];
        sd += d;  sdd = fmaf(d, d, sdd);
        sr += dr; srr = fmaf(dr, dr, srr);
    }
    atomicAdd(&sums[t],        sd);
    atomicAdd(&sums[256 + t],  sdd);
    atomicAdd(&sums[512 + t],  sr);
    atomicAdd(&sums[768 + t],  srr);
}

// ---- finalize stats (ddof=1) + repack W2/b2 ----
__global__ __launch_bounds__(256) void finalize_kernel(
    const float* __restrict__ sums, const float* __restrict__ W2, const float* __restrict__ b2,
    float* __restrict__ stats, float* __restrict__ W2p, float* __restrict__ b2p)
{
    const int t = threadIdx.x;
    const float M = (float)(BB * NN);
    {   const float s = sums[t], q = sums[256 + t];
        const float mean = s / M;
        float var = (q - s * mean) / (M - 1.0f);
        if (var < 1e-20f) var = 1e-20f;
        stats[t] = mean; stats[256 + t] = rsqrtf(var);
    }
    {   const float s = sums[512 + t], q = sums[768 + t];
        const float mean = s / M;
        float var = (q - s * mean) / (M - 1.0f);
        if (var < 1e-20f) var = 1e-20f;
        stats[512 + t] = mean; stats[768 + t] = rsqrtf(var);
    }
    for (int idx = t; idx < 1024; idx += 256) {
        const int k = idx >> 5, m = idx & 31;
        W2p[idx] = (m < 30) ? W2[k * 30 + m] : 0.0f;
    }
    if (t < 32) b2p[t] = (t < 30) ? b2[t] : 0.0f;
}

// ---- per-node projections: us = x@W1[0:12], ut' = x@W1[13:25] + c_a + b1 ----
__global__ __launch_bounds__(256) void node_pre_kernel(
    const float* __restrict__ x, const float* __restrict__ W1, const float* __restrict__ b1,
    float* __restrict__ usg, float* __restrict__ utpg)
{
    const int idx = blockIdx.x * 256 + threadIdx.x;
    const int r = idx >> 5, k = idx & 31;
    const float* xr = x + r * FF;
    float us = 0.f, ut = 0.f;
#pragma unroll
    for (int f = 0; f < FF; ++f) {
        const float xv = xr[f];
        us = fmaf(xv, W1[f * 32 + k], us);
        ut = fmaf(xv, W1[(13 + f) * 32 + k], ut);
    }
    const float ca = W1[12 * 32 + k] + W1[25 * 32 + k] + W1[27 * 32 + k]
                   + W1[29 * 32 + k] + W1[30 * 32 + k] + W1[31 * 32 + k];
    usg[idx]  = us;
    utpg[idx] = ut + ca + b1[k];
}

// ---- main edge kernel, MFMA layer-2 ----
// Lane l of wave w owns A-rows j=(l&15)+16*jt+64w (jt=0..3) and k-chunk (l>>4)*8..+7.
// A and B frags are packed with the SAME (group,elem)->k map, so HW k-ordering cancels.
// D layout (m89-verified): col m = l&15 (+16*mt), row j = (l>>4)*4 + reg (+16*jt).
// LDS: mins (pre-sync) and ldst (post-sync) are temporally disjoint -> aliased pool.
__global__ __launch_bounds__(256, 2) void edge_mfma_kernel(
    const float* __restrict__ adj_dist, const float* __restrict__ adj_direct,
    const float* __restrict__ W1, const float* __restrict__ b1,
    const float* __restrict__ usg, const float* __restrict__ utpg,
    const float* __restrict__ stats, const float* __restrict__ W2p,
    const float* __restrict__ b2p, float* __restrict__ plus,
    float* __restrict__ minusv, int lognit)
{
    __shared__ float us_s[64][32];     // i-tile rows of us (8 KB)
    __shared__ float pool[8192];       // 32 KB: mins[64][4][32] then ldst[30][257]
    float (*mins)[4][32] = reinterpret_cast<float(*)[4][32]>(pool);
    float (*ldst)[257]   = reinterpret_cast<float(*)[257]>(pool);

    const int t    = threadIdx.x;
    const int nit  = 1 << lognit;
    const int R    = NN >> lognit;     // 16 (lognit=4) / 32 / 64
    const int b    = blockIdx.x >> lognit;
    const int it   = blockIdx.x & (nit - 1);
    const int i0   = it * R;
    const int w    = t >> 6;
    const int l    = t & 63;
    const int m0   = l & 15;           // A-row-in-tile / B,D col
    const int g    = l >> 4;           // k-group: k = 8g..8g+7
    const int kb   = g << 3;

    // stage us rows
    { const int k = t & 31;
      for (int ii = t >> 5; ii < R; ii += 8)
          us_s[ii][k] = usg[((b << 8) + i0 + ii) * 32 + k]; }
    __syncthreads();

    // per-lane loop-invariant chunks (k = kb..kb+7)
    float b1c[8], r26c[8], r28c[8];
#pragma unroll
    for (int e = 0; e < 8; ++e) {
        b1c[e]  = b1[kb + e];
        r26c[e] = W1[26 * 32 + kb + e];
        r28c[e] = W1[28 * 32 + kb + e];
    }
    // utp chunks for my 4 j-rows
    float utpc[4][8];
#pragma unroll
    for (int jt = 0; jt < 4; ++jt) {
        const int j = (w << 6) + m0 + (jt << 4);
        const float4* uv = (const float4*)(utpg + ((b << 8) + j) * 32 + kb);
        float4 a0 = uv[0], a1 = uv[1];
        utpc[jt][0]=a0.x; utpc[jt][1]=a0.y; utpc[jt][2]=a0.z; utpc[jt][3]=a0.w;
        utpc[jt][4]=a1.x; utpc[jt][5]=a1.y; utpc[jt][6]=a1.z; utpc[jt][7]=a1.w;
    }
    // per-j stats for my 4 j-rows
    float mdp[4], isdp[4], mrp[4], isrp[4];
#pragma unroll
    for (int jt = 0; jt < 4; ++jt) {
        const int j = (w << 6) + m0 + (jt << 4);
        mdp[jt] = stats[j];        isdp[jt] = stats[256 + j];
        mrp[jt] = stats[512 + j];  isrp[jt] = stats[768 + j];
    }
    // W2 B-fragments: m = m0 + 16*mt, k = kb+e; split hi/lo for f32-accurate product
    bf16x8 whi[2], wlo[2];
#pragma unroll
    for (int mt = 0; mt < 2; ++mt) {
        const int m = m0 + (mt << 4);
#pragma unroll
        for (int e = 0; e < 8; ++e) {
            const float wv = W2p[(kb + e) * 32 + m];
            const short h16 = f2bf(wv);
            whi[mt][e] = h16;
            wlo[mt][e] = f2bf(wv - bf2f(h16));
        }
    }
    const float b2c[2] = { b2p[m0], b2p[m0 + 16] };
    const bool mt1ok = (m0 < 14);      // m = m0+16 valid iff < 30

    float accp[4][2][4];
#pragma unroll
    for (int jt = 0; jt < 4; ++jt)
#pragma unroll
        for (int mt = 0; mt < 2; ++mt)
#pragma unroll
            for (int r = 0; r < 4; ++r) accp[jt][mt][r] = 0.0f;

    const float* dptr = adj_dist   + (((b << 8) + i0) << 8) + t;
    const float* rptr = adj_direct + (((b << 8) + i0) << 8) + t;
    float dN = dptr[0], rN = rptr[0];

#pragma unroll 1
    for (int i = 0; i < R; ++i) {
        const float dcur = dN, rcur = rN;
        if (i + 1 < R) { dN = dptr[(i + 1) << 8]; rN = rptr[(i + 1) << 8]; }

        // us chunk for this i (wave-uniform per g: broadcast ds_read)
        float usc[8];
        { const float4* uv = (const float4*)&us_s[i][kb];
          float4 a0 = uv[0], a1 = uv[1];
          usc[0]=a0.x; usc[1]=a0.y; usc[2]=a0.z; usc[3]=a0.w;
          usc[4]=a1.x; usc[5]=a1.y; usc[6]=a1.z; usc[7]=a1.w; }

        // layer 1 -> A-fragments (bf16), one per jtile
        bf16x8 afr[4];
#pragma unroll
        for (int jt = 0; jt < 4; ++jt) {
            const float dv = __shfl(dcur, m0 + (jt << 4));
            const float rv = __shfl(rcur, m0 + (jt << 4));
            const bool  a  = (dv != 0.0f);
            const float dn = (dv - mdp[jt]) * isdp[jt];
            const float rn = (rv - mrp[jt]) * isrp[jt];
#pragma unroll
            for (int e = 0; e < 8; ++e) {
                float z = a ? (usc[e] + utpc[jt][e]) : b1c[e];
                z = fmaf(dn, r26c[e], z);
                z = fmaf(rn, r28c[e], z);
                afr[jt][e] = f2bf(sig(z));
            }
        }

        // layer 2 via MFMA + sigmoid + accumulate
        float msum0 = 0.0f, msum1 = 0.0f;
#pragma unroll
        for (int jt = 0; jt < 4; ++jt) {
#pragma unroll
            for (int mt = 0; mt < 2; ++mt) {
                f32x4 d4 = {0.f, 0.f, 0.f, 0.f};
                d4 = __builtin_amdgcn_mfma_f32_16x16x32_bf16(afr[jt], wlo[mt], d4, 0, 0, 0);
                d4 = __builtin_amdgcn_mfma_f32_16x16x32_bf16(afr[jt], whi[mt], d4, 0, 0, 0);
#pragma unroll
                for (int r = 0; r < 4; ++r) {
                    float e = sig(d4[r] + b2c[mt]);
                    if (mt == 1 && !mt1ok) e = 0.0f;
                    accp[jt][mt][r] += e;
                    if (mt == 0) msum0 += e; else msum1 += e;
                }
            }
        }
        // minus: all-reduce over k-groups (j coverage: jt x g x reg = 64 rows)
        msum0 += __shfl_xor(msum0, 16); msum0 += __shfl_xor(msum0, 32);
        msum1 += __shfl_xor(msum1, 16); msum1 += __shfl_xor(msum1, 32);
        if (l < 16) { mins[i][w][l] = msum0; mins[i][w][l + 16] = msum1; }
    }
    __syncthreads();

    // minus flush: complete col-sums for this block's rows -> plain stores
    { const int m = t & 31;
      if (m < 30)
          for (int ii = t >> 5; ii < R; ii += 8) {
              const float s = mins[ii][0][m] + mins[ii][1][m]
                            + mins[ii][2][m] + mins[ii][3][m];
              minusv[((b << 5) + m) * 256 + i0 + ii] = s;
          } }
    __syncthreads();   // pool reuse boundary: mins -> ldst

    // plus: transpose through LDS then coalesced store
#pragma unroll
    for (int jt = 0; jt < 4; ++jt)
#pragma unroll
        for (int mt = 0; mt < 2; ++mt) {
            const int m = m0 + (mt << 4);
            if (m < 30) {
#pragma unroll
                for (int r = 0; r < 4; ++r) {
                    const int j = (w << 6) + (jt << 4) + (g << 2) + r;
                    ldst[m][j] = accp[jt][mt][r];
                }
            }
        }
    __syncthreads();
    { const int base = ((b << lognit) + it) << 13;
#pragma unroll
      for (int m = 0; m < 30; ++m)
          plus[base + (m << 8) + t] = ldst[m][t];
    }
}

// ---- reduce partials + node MLP, fused ----
__global__ __launch_bounds__(256) void reduce_out_kernel(
    const float* __restrict__ plus, const float* __restrict__ minusv,
    const float* __restrict__ W3, const float* __restrict__ b3,
    float* __restrict__ out, int lognit)
{
    const int b = blockIdx.x;
    const int n = threadIdx.x;
    const int nit = 1 << lognit;

    float acc[30];
#pragma unroll
    for (int m = 0; m < 30; ++m) acc[m] = -minusv[((b << 5) + m) * 256 + n];
#pragma unroll 1
    for (int it = 0; it < nit; ++it) {
        const float* p = plus + (((b << lognit) + it) << 13) + n;
#pragma unroll
        for (int m = 0; m < 30; ++m) acc[m] += p[m << 8];
    }
    float* op = out + ((b << 8) + n) * 12;
#pragma unroll
    for (int o = 0; o < 12; ++o) {
        float z = b3[o];
#pragma unroll
        for (int m = 0; m < 30; ++m) z = fmaf(acc[m], W3[m * 12 + o], z);
        op[o] = sig(z);
    }
}

extern "C" void kernel_launch(void* const* d_in, const int* in_sizes, int n_in,
                              void* d_out, int out_size, void* d_ws, size_t ws_size,
                              hipStream_t stream)
{
    const float* x    = (const float*)d_in[0];
    const float* adjd = (const float*)d_in[1];
    const float* adjr = (const float*)d_in[2];
    const float* W1   = (const float*)d_in[5];
    const float* b1   = (const float*)d_in[6];
    const float* W2   = (const float*)d_in[7];
    const float* b2   = (const float*)d_in[8];
    const float* W3   = (const float*)d_in[9];
    const float* b3   = (const float*)d_in[10];
    float* ws  = (float*)d_ws;
    float* out = (float*)d_out;

    // pick i-tile count from available scratch (deterministic across calls)
    int lognit = 2;                                            // 64 rows/blk
    if      (ws_size >= ((size_t)WS_PLUS + 16u * 262144u) * 4u) lognit = 4;  // 16 rows
    else if (ws_size >= ((size_t)WS_PLUS +  8u * 262144u) * 4u) lognit = 3;  // 32 rows

    hipMemsetAsync(ws + WS_SUMS, 0, 1024 * sizeof(float), stream);

    colstats_kernel<<<256, 256, 0, stream>>>(adjd, adjr, ws + WS_SUMS);
    node_pre_kernel<<<1024, 256, 0, stream>>>(x, W1, b1, ws + WS_USG, ws + WS_UTPG);
    finalize_kernel<<<1, 256, 0, stream>>>(ws + WS_SUMS, W2, b2,
                                           ws + WS_STATS, ws + WS_W2P, ws + WS_B2P);
    edge_mfma_kernel<<<BB << lognit, 256, 0, stream>>>(adjd, adjr, W1, b1,
                                                       ws + WS_USG, ws + WS_UTPG,
                                                       ws + WS_STATS, ws + WS_W2P,
                                                       ws + WS_B2P, ws + WS_PLUS,
                                                       ws + WS_MIN, lognit);
    reduce_out_kernel<<<BB, 256, 0, stream>>>(ws + WS_PLUS, ws + WS_MIN,
                                              W3, b3, out, lognit);
}

// Round 6
// 149.841 us; speedup vs baseline: 4.4909x; 1.1095x over previous
//
#include <hip/hip_runtime.h>
#include <hip/hip_bf16.h>
#include <math.h>

// Problem constants
#define BB 32
#define NN 256
#define FF 12
// ws layout (in floats)
#define WS_SUMS   0                    // 1024: sum_d, sumsq_d, sum_r, sumsq_r (256 each)
#define WS_STATS  1024                 // 1024: mean_d, istd_d, mean_r, istd_r (256 each)
#define WS_W2P    2048                 // 1024: W2 repacked [32][32] (m padded 30->32)
#define WS_B2P    3072                 // 32 (+pad to 1024)
#define WS_USG    4096                 // 262144: us[b][i][32]
#define WS_UTPG   266240               // 262144: ut'[b][j][32] = ut + c_a + b1
#define WS_MIN    528384               // 524288: minus[b][jh][m][n] partial col-sums
#define WS_PLUS   1052672              // nit*262144: plus[b][it][m][j] partials

typedef __attribute__((ext_vector_type(8))) short bf16x8;
typedef __attribute__((ext_vector_type(4))) float f32x4;

// fast sigmoid: v_exp_f32 + v_rcp_f32
__device__ __forceinline__ float sig(float x) {
    return __builtin_amdgcn_rcpf(1.0f + __expf(-x));
}
__device__ __forceinline__ short f2bf(float x) {
    __hip_bfloat16 b = __float2bfloat16(x);   // RTN-even (prologue only)
    short s; __builtin_memcpy(&s, &b, 2); return s;
}
__device__ __forceinline__ float bf2f(short s) {
    __hip_bfloat16 b; __builtin_memcpy(&b, &s, 2);
    return __bfloat162float(b);
}
// truncation pair-pack: two f32 -> two bf16 in one u32 (lo in low half)
__device__ __forceinline__ unsigned pkbf(float lo, float hi) {
    unsigned ulo, uhi;
    __builtin_memcpy(&ulo, &lo, 4); __builtin_memcpy(&uhi, &hi, 4);
    return (uhi & 0xffff0000u) | (ulo >> 16);
}

// ---- per-column (j) stats partial sums over (b,i) ----
__global__ __launch_bounds__(256) void colstats_kernel(
    const float* __restrict__ dist, const float* __restrict__ direc, float* __restrict__ sums)
{
    const int t = threadIdx.x;
    const int r0 = blockIdx.x * 32;
    float sd = 0.f, sdd = 0.f, sr = 0.f, srr = 0.f;
#pragma unroll 4
    for (int rr = 0; rr < 32; ++rr) {
        const float d  = dist [(r0 + rr) * NN + t];
        const float dr = direc[(r0 + rr) * NN + t];
        sd += d;  sdd = fmaf(d, d, sdd);
        sr += dr; srr = fmaf(dr, dr, srr);
    }
    atomicAdd(&sums[t],        sd);
    atomicAdd(&sums[256 + t],  sdd);
    atomicAdd(&sums[512 + t],  sr);
    atomicAdd(&sums[768 + t],  srr);
}

// ---- finalize stats (ddof=1) + repack W2/b2 ----
__global__ __launch_bounds__(256) void finalize_kernel(
    const float* __restrict__ sums, const float* __restrict__ W2, const float* __restrict__ b2,
    float* __restrict__ stats, float* __restrict__ W2p, float* __restrict__ b2p)
{
    const int t = threadIdx.x;
    const float M = (float)(BB * NN);
    {   const float s = sums[t], q = sums[256 + t];
        const float mean = s / M;
        float var = (q - s * mean) / (M - 1.0f);
        if (var < 1e-20f) var = 1e-20f;
        stats[t] = mean; stats[256 + t] = rsqrtf(var);
    }
    {   const float s = sums[512 + t], q = sums[768 + t];
        const float mean = s / M;
        float var = (q - s * mean) / (M - 1.0f);
        if (var < 1e-20f) var = 1e-20f;
        stats[512 + t] = mean; stats[768 + t] = rsqrtf(var);
    }
    for (int idx = t; idx < 1024; idx += 256) {
        const int k = idx >> 5, m = idx & 31;
        W2p[idx] = (m < 30) ? W2[k * 30 + m] : 0.0f;
    }
    if (t < 32) b2p[t] = (t < 30) ? b2[t] : 0.0f;
}

// ---- per-node projections: us = x@W1[0:12], ut' = x@W1[13:25] + c_a + b1 ----
__global__ __launch_bounds__(256) void node_pre_kernel(
    const float* __restrict__ x, const float* __restrict__ W1, const float* __restrict__ b1,
    float* __restrict__ usg, float* __restrict__ utpg)
{
    const int idx = blockIdx.x * 256 + threadIdx.x;
    const int r = idx >> 5, k = idx & 31;
    const float* xr = x + r * FF;
    float us = 0.f, ut = 0.f;
#pragma unroll
    for (int f = 0; f < FF; ++f) {
        const float xv = xr[f];
        us = fmaf(xv, W1[f * 32 + k], us);
        ut = fmaf(xv, W1[(13 + f) * 32 + k], ut);
    }
    const float ca = W1[12 * 32 + k] + W1[25 * 32 + k] + W1[27 * 32 + k]
                   + W1[29 * 32 + k] + W1[30 * 32 + k] + W1[31 * 32 + k];
    usg[idx]  = us;
    utpg[idx] = ut + ca + b1[k];
}

// ---- main edge kernel, MFMA layer-2, j-split x2 for occupancy ----
// Block = (b, it, jh): i in [it*R, +R), j in [jh*128, +128). 4 waves x 32 j each.
// Lane l: m0 = l&15 (A-row / D-col), g = l>>4 (k-chunk 8g..8g+7); jt in {0,1}.
// D layout (m89-verified): col m = (l&15)+16*mt, row j_loc = (l>>4)*4 + reg.
// LDS pool: mins (pre-sync) aliases ldst (post-sync).
__global__ __launch_bounds__(256, 4) void edge_mfma_kernel(
    const float* __restrict__ adj_dist, const float* __restrict__ adj_direct,
    const float* __restrict__ W1, const float* __restrict__ b1,
    const float* __restrict__ usg, const float* __restrict__ utpg,
    const float* __restrict__ stats, const float* __restrict__ W2p,
    const float* __restrict__ b2p, float* __restrict__ plus,
    float* __restrict__ minusv, int lognit)
{
    __shared__ float us_s[64][32];     // 8 KB (R <= 64)
    __shared__ float pool[8192];       // 32 KB: mins[64][4][32] then ldst[30][129]
    float (*mins)[4][32] = reinterpret_cast<float(*)[4][32]>(pool);
    float (*ldst)[129]   = reinterpret_cast<float(*)[129]>(pool);

    const int t    = threadIdx.x;
    const int nit  = 1 << lognit;
    const int R    = NN >> lognit;     // 16 at lognit=4
    const int bid  = blockIdx.x;
    const int b    = bid >> (lognit + 1);
    const int it   = (bid >> 1) & (nit - 1);
    const int jh   = bid & 1;
    const int i0   = it * R;
    const int w    = t >> 6;
    const int l    = t & 63;
    const int m0   = l & 15;
    const int g    = l >> 4;
    const int kb   = g << 3;
    const int jbase = (jh << 7) + (w << 5);   // wave's first (global) j

    // stage us rows
    { const int k = t & 31;
      for (int ii = t >> 5; ii < R; ii += 8)
          us_s[ii][k] = usg[((b << 8) + i0 + ii) * 32 + k]; }
    __syncthreads();

    // loop-invariant per-lane chunks (k = kb..kb+7)
    float b1c[8], r26c[8], r28c[8];
#pragma unroll
    for (int e = 0; e < 8; ++e) {
        b1c[e]  = b1[kb + e];
        r26c[e] = W1[26 * 32 + kb + e];
        r28c[e] = W1[28 * 32 + kb + e];
    }
    float utpc[2][8];
#pragma unroll
    for (int jt = 0; jt < 2; ++jt) {
        const int j = jbase + (jt << 4) + m0;
        const float4* uv = (const float4*)(utpg + ((b << 8) + j) * 32 + kb);
        float4 a0 = uv[0], a1 = uv[1];
        utpc[jt][0]=a0.x; utpc[jt][1]=a0.y; utpc[jt][2]=a0.z; utpc[jt][3]=a0.w;
        utpc[jt][4]=a1.x; utpc[jt][5]=a1.y; utpc[jt][6]=a1.z; utpc[jt][7]=a1.w;
    }
    float mdp[2], isdp[2], mrp[2], isrp[2];
#pragma unroll
    for (int jt = 0; jt < 2; ++jt) {
        const int j = jbase + (jt << 4) + m0;
        mdp[jt] = stats[j];        isdp[jt] = stats[256 + j];
        mrp[jt] = stats[512 + j];  isrp[jt] = stats[768 + j];
    }
    // W2 B-fragments, hi/lo split (f32-accurate product; extra MFMA is free)
    bf16x8 whi[2], wlo[2];
#pragma unroll
    for (int mt = 0; mt < 2; ++mt) {
        const int m = m0 + (mt << 4);
#pragma unroll
        for (int e = 0; e < 8; ++e) {
            const float wv = W2p[(kb + e) * 32 + m];
            const short h16 = f2bf(wv);
            whi[mt][e] = h16;
            wlo[mt][e] = f2bf(wv - bf2f(h16));
        }
    }
    const float b2c[2] = { b2p[m0], b2p[m0 + 16] };
    const bool mt1ok = (m0 < 14);      // m = m0+16 valid iff < 30

    float accp[2][2][4];
#pragma unroll
    for (int jt = 0; jt < 2; ++jt)
#pragma unroll
        for (int mt = 0; mt < 2; ++mt)
#pragma unroll
            for (int r = 0; r < 4; ++r) accp[jt][mt][r] = 0.0f;

    const int col = (jh << 7) + (w << 5) + (l & 31);   // lanes 32-63 duplicate 0-31
    const float* dptr = adj_dist   + (((b << 8) + i0) << 8) + col;
    const float* rptr = adj_direct + (((b << 8) + i0) << 8) + col;
    float dN = dptr[0], rN = rptr[0];

#pragma unroll 1
    for (int i = 0; i < R; ++i) {
        const float dcur = dN, rcur = rN;
        if (i + 1 < R) { dN = dptr[(i + 1) << 8]; rN = rptr[(i + 1) << 8]; }

        // us chunk for this i (wave-uniform per g: broadcast ds_read)
        float usc[8];
        { const float4* uv = (const float4*)&us_s[i][kb];
          float4 a0 = uv[0], a1 = uv[1];
          usc[0]=a0.x; usc[1]=a0.y; usc[2]=a0.z; usc[3]=a0.w;
          usc[4]=a1.x; usc[5]=a1.y; usc[6]=a1.z; usc[7]=a1.w; }

        // layer 1 -> A-fragments (bf16 via trunc pair-pack)
        bf16x8 afr[2];
#pragma unroll
        for (int jt = 0; jt < 2; ++jt) {
            const int src = (jt << 4) + m0;            // lane < 32
            const float dv = __shfl(dcur, src);
            const float rv = __shfl(rcur, src);
            const bool  a  = (dv != 0.0f);
            const float dn = (dv - mdp[jt]) * isdp[jt];
            const float rn = (rv - mrp[jt]) * isrp[jt];
            float h[8];
#pragma unroll
            for (int e = 0; e < 8; ++e) {
                float z = a ? (usc[e] + utpc[jt][e]) : b1c[e];
                z = fmaf(dn, r26c[e], z);
                z = fmaf(rn, r28c[e], z);
                h[e] = sig(z);
            }
            union { bf16x8 v; unsigned u[4]; } af;
#pragma unroll
            for (int p = 0; p < 4; ++p) af.u[p] = pkbf(h[2*p], h[2*p+1]);
            afr[jt] = af.v;
        }

        // layer 2 via MFMA (b2 folded into C init) + sigmoid + accumulate
        float msum0 = 0.0f, msum1 = 0.0f;
#pragma unroll
        for (int jt = 0; jt < 2; ++jt) {
#pragma unroll
            for (int mt = 0; mt < 2; ++mt) {
                f32x4 d4 = { b2c[mt], b2c[mt], b2c[mt], b2c[mt] };
                d4 = __builtin_amdgcn_mfma_f32_16x16x32_bf16(afr[jt], wlo[mt], d4, 0, 0, 0);
                d4 = __builtin_amdgcn_mfma_f32_16x16x32_bf16(afr[jt], whi[mt], d4, 0, 0, 0);
#pragma unroll
                for (int r = 0; r < 4; ++r) {
                    float e = sig(d4[r]);
                    if (mt == 1 && !mt1ok) e = 0.0f;
                    accp[jt][mt][r] += e;
                    if (mt == 0) msum0 += e; else msum1 += e;
                }
            }
        }
        // minus: reduce over the 4 k-groups (rows covered: jt x g x reg = 32 j)
        msum0 += __shfl_xor(msum0, 16); msum0 += __shfl_xor(msum0, 32);
        msum1 += __shfl_xor(msum1, 16); msum1 += __shfl_xor(msum1, 32);
        if (l < 16) { mins[i][w][l] = msum0; mins[i][w][l + 16] = msum1; }
    }
    __syncthreads();

    // minus flush: this block's partial (over its 128 j) -> plain store
    { const int m = t & 31;
      if (m < 30)
          for (int ii = t >> 5; ii < R; ii += 8) {
              const float s = mins[ii][0][m] + mins[ii][1][m]
                            + mins[ii][2][m] + mins[ii][3][m];
              minusv[((b * 2 + jh) * 32 + m) * 256 + i0 + ii] = s;
          } }
    __syncthreads();   // pool reuse boundary: mins -> ldst

    // plus: transpose through LDS then coalesced store
#pragma unroll
    for (int jt = 0; jt < 2; ++jt)
#pragma unroll
        for (int mt = 0; mt < 2; ++mt) {
            const int m = m0 + (mt << 4);
            if (m < 30) {
#pragma unroll
                for (int r = 0; r < 4; ++r) {
                    const int jl = (w << 5) + (jt << 4) + (g << 2) + r;  // 0..127
                    ldst[m][jl] = accp[jt][mt][r];
                }
            }
        }
    __syncthreads();
    { const int base = ((b << lognit) + it) << 13;    // (b*nit+it)*32*256
      const int jl = t & 127;
#pragma unroll
      for (int mi = 0; mi < 15; ++mi) {
          const int m = (mi << 1) + (t >> 7);         // 30 m-rows by 2 half-blocks
          plus[base + (m << 8) + (jh << 7) + jl] = ldst[m][jl];
      }
    }
}

// ---- reduce partials + node MLP, fused; grid = BB*8 ----
__global__ __launch_bounds__(256) void reduce_out_kernel(
    const float* __restrict__ plus, const float* __restrict__ minusv,
    const float* __restrict__ W3, const float* __restrict__ b3,
    float* __restrict__ out, int lognit)
{
    __shared__ float agg_s[32][33];
    const int b   = blockIdx.x >> 3;
    const int nh  = blockIdx.x & 7;
    const int t   = threadIdx.x;
    const int nl  = t & 31;
    const int n   = (nh << 5) + nl;
    const int mg  = t >> 5;            // m = 4*mg .. 4*mg+3
    const int nit = 1 << lognit;

    float acc[4] = {0.f, 0.f, 0.f, 0.f};
#pragma unroll 1
    for (int it = 0; it < nit; ++it) {
        const float* p = plus + (((b << lognit) + it) << 13) + n;
#pragma unroll
        for (int q = 0; q < 4; ++q) acc[q] += p[((mg << 2) + q) << 8];
    }
#pragma unroll
    for (int q = 0; q < 4; ++q) {
        const int m = (mg << 2) + q;
        float v = acc[q]
                - minusv[((b * 2 + 0) * 32 + m) * 256 + n]
                - minusv[((b * 2 + 1) * 32 + m) * 256 + n];
        agg_s[nl][m] = (m < 30) ? v : 0.0f;   // m>=30 slots are poison -> mask
    }
    __syncthreads();

    // node MLP: 32 n x 12 o = 384 tasks
    for (int task = t; task < 384; task += 256) {
        const int n2 = task / 12, o = task % 12;
        float z = b3[o];
#pragma unroll
        for (int m = 0; m < 30; ++m) z = fmaf(agg_s[n2][m], W3[m * 12 + o], z);
        out[(((b << 8) + (nh << 5) + n2) * 12) + o] = sig(z);
    }
}

extern "C" void kernel_launch(void* const* d_in, const int* in_sizes, int n_in,
                              void* d_out, int out_size, void* d_ws, size_t ws_size,
                              hipStream_t stream)
{
    const float* x    = (const float*)d_in[0];
    const float* adjd = (const float*)d_in[1];
    const float* adjr = (const float*)d_in[2];
    const float* W1   = (const float*)d_in[5];
    const float* b1   = (const float*)d_in[6];
    const float* W2   = (const float*)d_in[7];
    const float* b2   = (const float*)d_in[8];
    const float* W3   = (const float*)d_in[9];
    const float* b3   = (const float*)d_in[10];
    float* ws  = (float*)d_ws;
    float* out = (float*)d_out;

    // pick i-tile count from available scratch (deterministic across calls)
    int lognit = 2;                                                          // 7.4 MB
    if      (ws_size >= ((size_t)WS_PLUS + 16u * 262144u) * 4u) lognit = 4;  // 21 MB
    else if (ws_size >= ((size_t)WS_PLUS +  8u * 262144u) * 4u) lognit = 3;  // 12.6 MB

    hipMemsetAsync(ws + WS_SUMS, 0, 1024 * sizeof(float), stream);

    colstats_kernel<<<256, 256, 0, stream>>>(adjd, adjr, ws + WS_SUMS);
    node_pre_kernel<<<1024, 256, 0, stream>>>(x, W1, b1, ws + WS_USG, ws + WS_UTPG);
    finalize_kernel<<<1, 256, 0, stream>>>(ws + WS_SUMS, W2, b2,
                                           ws + WS_STATS, ws + WS_W2P, ws + WS_B2P);
    edge_mfma_kernel<<<BB << (lognit + 1), 256, 0, stream>>>(adjd, adjr, W1, b1,
                                                             ws + WS_USG, ws + WS_UTPG,
                                                             ws + WS_STATS, ws + WS_W2P,
                                                             ws + WS_B2P, ws + WS_PLUS,
                                                             ws + WS_MIN, lognit);
    reduce_out_kernel<<<BB * 8, 256, 0, stream>>>(ws + WS_PLUS, ws + WS_MIN,
                                                  W3, b3, out, lognit);
}